// Round 7
// baseline (126.648 us; speedup 1.0000x reference)
//
#include <hip/hip_runtime.h>

// log2-domain "log 0": exp2(-30000) == 0, exactly representable in half, never NaN.
#define NEG2 (-30000.0f)
#define L2E  1.4426950408889634f
#define LN2  0.6931471805599453f

constexpr int B = 8, T = 128, U = 64, U1 = 65, V = 512;
constexpr int NW = 16;                            // waves per block
constexpr size_t ETH_TOT = (size_t)B * T * V;     // halves

typedef _Float16 half_t;
typedef _Float16 v4h __attribute__((ext_vector_type(4)));
typedef _Float16 v8h __attribute__((ext_vector_type(8)));
typedef float    v4f __attribute__((ext_vector_type(4)));

__device__ __forceinline__ float wave_shr1(float x) {  // lane i <- lane i-1 (lane0 keeps own)
    int v = __float_as_int(x);
    int r = __builtin_amdgcn_update_dpp(v, v, 0x138, 0xF, 0xF, false); // wave_shr:1
    return __int_as_float(r);
}

__device__ __forceinline__ float dp_step(float cur, uint w, float a00, int d, int l, int tl) {
    const int t = d - l - 1;
    union { uint u; half_t h[2]; } cv; cv.u = w;
    const float bn = (float)cv.h[0];       // blank~[t-1][u]
    const float lb = (float)cv.h[1];       // lab~[t][u-1]
    const float sh = wave_shr1(cur);
    const float lv = (l == 0) ? a00 : sh;  // alpha[t][u-1]
    const float a2 = lv + lb;
    const float a1 = (t >= 1) ? cur + bn : NEG2;
    const float m  = fmaxf(a1, a2);
    const float nc = m + __log2f(exp2f(a1 - m) + exp2f(a2 - m));
    return ((t >= 0) && (t <= tl)) ? nc : cur;
}

// One block per batch element, 16 waves: prep(SW-pipelined) -> joint(MFMA, pipelined
// fragment loads, epilogue to LDS) -> DP (wave 0).
__global__ __launch_bounds__(1024) void k_fused(const float* __restrict__ trans,
                                                const float* __restrict__ pred,
                                                const int* __restrict__ labels,
                                                const int* __restrict__ act_lens,
                                                const int* __restrict__ label_lens,
                                                float* __restrict__ ws,
                                                float* __restrict__ out) {
    const int b   = blockIdx.x;
    const int tid = threadIdx.x;
    const int wid = tid >> 6;      // 0..15
    const int l   = tid & 63;

    __shared__ uint   Pds[192 * 64];   // 48 KB diag lattice: row r=d-1; x=blank~[r-c-1][c+1], y=lab~[r-c][c]
    __shared__ float  af[T];           // alpha~[t][0]
    __shared__ float  C0[T];           // blank~[t][0]
    __shared__ float  MT[T], T0[T];
    __shared__ float  MP[U1], P0[U1], PL[U1];
    __shared__ half_t TL[T * 64];      // trans[t][labels[u]] 16 KB

    half_t* wsh  = (half_t*)ws;
    half_t* ethb = wsh + (size_t)b * T * V;             // this b's exp(trans) f16 rows
    half_t* ephb = wsh + ETH_TOT + (size_t)b * U1 * V;  // this b's exp(pred) f16 rows

    const int ul = label_lens[b];          // in [32,64]
    const int tl = act_lens[b] - 1;        // >= 63
    const int mylbl = labels[b * U + l];   // lane == u (l < 64 == U)

    // ---- phase 1: row max + exp (f16) + gathers; 2-row software pipeline ----
    {
        const int NR = T + U1;             // 193 rows
        int r = wid;
        const float* src = (r < T) ? trans + ((size_t)b * T + r) * V
                                   : pred + ((size_t)b * U1 + (r - T)) * V;
        float4 a = ((const float4*)src)[l];
        float4 c = ((const float4*)src)[l + 64];
        while (true) {
            const int rn = r + NW;
            const float* src2 = src;
            float4 a2, c2;
            if (rn < NR) {                 // issue next row's loads before this row's math
                src2 = (rn < T) ? trans + ((size_t)b * T + rn) * V
                                : pred + ((size_t)b * U1 + (rn - T)) * V;
                a2 = ((const float4*)src2)[l];
                c2 = ((const float4*)src2)[l + 64];
            }

            float m = fmaxf(fmaxf(fmaxf(a.x, a.y), fmaxf(a.z, a.w)),
                            fmaxf(fmaxf(c.x, c.y), fmaxf(c.z, c.w)));
            #pragma unroll
            for (int off = 32; off >= 1; off >>= 1) m = fmaxf(m, __shfl_xor(m, off));

            v4h h0 = { (half_t)__expf(a.x - m), (half_t)__expf(a.y - m),
                       (half_t)__expf(a.z - m), (half_t)__expf(a.w - m) };
            v4h h1 = { (half_t)__expf(c.x - m), (half_t)__expf(c.y - m),
                       (half_t)__expf(c.z - m), (half_t)__expf(c.w - m) };
            if (r < T) {
                half_t* dst = ethb + (size_t)r * V;
                ((v4h*)dst)[l] = h0; ((v4h*)dst)[l + 64] = h1;
                TL[r * 64 + l] = (half_t)src[mylbl];              // L1-hot gather
                if (l == 0) { MT[r] = m; T0[r] = a.x; }
            } else {
                const int u = r - T;
                half_t* dst = ephb + (size_t)u * V;
                ((v4h*)dst)[l] = h0; ((v4h*)dst)[l + 64] = h1;
                if (l == u && l < U) PL[l] = src[mylbl];          // lane u owns its label
                if (l == 0) { MP[u] = m; P0[u] = a.x; }
            }

            if (rn >= NR) break;
            r = rn; src = src2; a = a2; c = c2;
        }
    }
    __syncthreads();

    // ---- phase 2: MFMA joint GEMM; 40 tile-tasks over 16 waves; frag-group pipeline ----
    {
        const int n = l & 15, q = l >> 4;
        for (int task = wid; task < 40; task += NW) {
            const int t0 = (task / 5) * 16, u0 = (task % 5) * 16;
            const v8h* A = (const v8h*)(ethb + (size_t)(t0 + n) * V);
            const int uc = (u0 + n <= 64) ? (u0 + n) : 64;
            const v8h* Bp = (const v8h*)(ephb + (size_t)uc * V);

            // frag index for MFMA step s (0..15) is s*4+q; pipeline groups of 4 steps
            v4f acc = {0.f, 0.f, 0.f, 0.f};
            v8h Aa[4], Ba[4], An[4], Bn[4];
            #pragma unroll
            for (int j = 0; j < 4; ++j) { Aa[j] = A[j * 4 + q]; Ba[j] = Bp[j * 4 + q]; }
            #pragma unroll
            for (int g = 0; g < 4; ++g) {
                if (g < 3) {
                    #pragma unroll
                    for (int j = 0; j < 4; ++j) {
                        An[j] = A[((g + 1) * 4 + j) * 4 + q];
                        Bn[j] = Bp[((g + 1) * 4 + j) * 4 + q];
                    }
                }
                #pragma unroll
                for (int j = 0; j < 4; ++j)
                    acc = __builtin_amdgcn_mfma_f32_16x16x32_f16(Aa[j], Ba[j], acc, 0, 0, 0);
                if (g < 3) {
                    #pragma unroll
                    for (int j = 0; j < 4; ++j) { Aa[j] = An[j]; Ba[j] = Bn[j]; }
                }
            }

            const int u = u0 + n;                  // C/D: col=lane&15 -> u, row=q*4+i -> t
            if (u > 64) continue;
            const float mp_u = MP[u], pr0 = P0[u];
            const bool has_lab = (u < 64);
            const float prl = has_lab ? PL[u] : 0.f;
            #pragma unroll
            for (int i = 0; i < 4; ++i) {
                const int t = t0 + q * 4 + i;
                const float lse2 = (MT[t] + mp_u) * L2E + __log2f(acc[i]);
                const float bl2 = (T0[t] + pr0) * L2E - lse2;     // blank~[t][u]
                const int row = t + u;                            // = d-1
                if (u >= 1) ((half_t*)&Pds[row * 64 + (u - 1)])[0] = (half_t)bl2;
                else        C0[t] = bl2;
                if (has_lab) {
                    const float lb2 = (u >= ul) ? NEG2
                                     : ((float)TL[t * 64 + u] + prl) * L2E - lse2;  // lab~[t][u]
                    ((half_t*)&Pds[row * 64 + u])[1] = (half_t)lb2;
                }
            }
        }
    }
    __syncthreads();

    // ---- phase 3: anti-diagonal DP, wave 0 only ----
    if (wid != 0) return;

    float x0 = C0[l], x1 = C0[64 + l];     // alpha0 column: prefix scan of C0
    #pragma unroll
    for (int off = 1; off < 64; off <<= 1) { float y = __shfl_up(x0, off); if (l >= off) x0 += y; }
    #pragma unroll
    for (int off = 1; off < 64; off <<= 1) { float y = __shfl_up(x1, off); if (l >= off) x1 += y; }
    const float tot = __shfl(x0, 63);
    if (l == 0) af[0] = 0.0f;
    af[l + 1] = x0;                        // t = 1..64
    if (l < 63) af[65 + l] = tot + x1;     // t = 65..127

    const int dmax = tl + ul;              // <= 191
    const int steps = (dmax + 3) >> 2;     // overshoot steps are no-ops (t>tl guard)

    uint  w0 = Pds[0 * 64 + l], w1 = Pds[1 * 64 + l], w2 = Pds[2 * 64 + l], w3 = Pds[3 * 64 + l];
    float a0 = af[0], a1 = af[1], a2 = af[2], a3 = af[3];

    float cur = 0.0f;                      // lane l owns u = l+1; at step d, t = d-l-1
    int d = 1;
    for (int s = 0; s < steps; ++s) {
        cur = dp_step(cur, w0, a0, d, l, tl);
        w0 = Pds[min(d + 3, 191) * 64 + l]; a0 = af[min(d + 3, T - 1)]; ++d;
        cur = dp_step(cur, w1, a1, d, l, tl);
        w1 = Pds[min(d + 3, 191) * 64 + l]; a1 = af[min(d + 3, T - 1)]; ++d;
        cur = dp_step(cur, w2, a2, d, l, tl);
        w2 = Pds[min(d + 3, 191) * 64 + l]; a2 = af[min(d + 3, T - 1)]; ++d;
        cur = dp_step(cur, w3, a3, d, l, tl);
        w3 = Pds[min(d + 3, 191) * 64 + l]; a3 = af[min(d + 3, T - 1)]; ++d;
    }

    if (l == ul - 1) {                     // cur == alpha~[tl][ul]
        union { uint u; half_t h[2]; } cv; cv.u = Pds[dmax * 64 + (ul - 1)]; // d = dmax+1
        atomicAdd(out, -((cur + (float)cv.h[0]) * LN2));
    }
}

extern "C" void kernel_launch(void* const* d_in, const int* in_sizes, int n_in,
                              void* d_out, int out_size, void* d_ws, size_t ws_size,
                              hipStream_t stream) {
    const float* trans      = (const float*)d_in[0];
    const float* pred       = (const float*)d_in[1];
    const int*   labels     = (const int*)d_in[2];
    const int*   act_lens   = (const int*)d_in[3];
    const int*   label_lens = (const int*)d_in[4];
    float* ws  = (float*)d_ws;
    float* out = (float*)d_out;

    hipMemsetAsync(out, 0, sizeof(float), stream);   // graph-capturable memset node
    k_fused<<<B, 1024, 0, stream>>>(trans, pred, labels, act_lens, label_lens, ws, out);
}

// Round 8
// 110.002 us; speedup vs baseline: 1.1513x; 1.1513x over previous
//
#include <hip/hip_runtime.h>

// log2-domain "log 0": exp2(-30000) == 0, exactly representable in half, never NaN.
#define NEG2 (-30000.0f)
#define L2E  1.4426950408889634f
#define LN2  0.6931471805599453f

constexpr int B = 8, T = 128, U = 64, U1 = 65, V = 512;
constexpr int NW = 16;                 // waves per block
constexpr int EPS = 520;               // padded LDS stride (halves) for exp(pred) rows

typedef _Float16 half_t;
typedef _Float16 v4h __attribute__((ext_vector_type(4)));
typedef _Float16 v8h __attribute__((ext_vector_type(8)));
typedef float    v4f __attribute__((ext_vector_type(4)));

__device__ __forceinline__ float wave_shr1(float x) {  // lane i <- lane i-1 (lane0 keeps own)
    int v = __float_as_int(x);
    int r = __builtin_amdgcn_update_dpp(v, v, 0x138, 0xF, 0xF, false); // wave_shr:1
    return __int_as_float(r);
}

__device__ __forceinline__ float dp_step(float cur, uint w, float a00, int d, int l, int tl) {
    const int t = d - l - 1;
    union { uint u; half_t h[2]; } cv; cv.u = w;
    const float bn = (float)cv.h[0];       // blank~[t-1][u]
    const float lb = (float)cv.h[1];       // lab~[t][u-1]
    const float sh = wave_shr1(cur);
    const float lv = (l == 0) ? a00 : sh;  // alpha[t][u-1]
    const float a2 = lv + lb;
    const float a1 = (t >= 1) ? cur + bn : NEG2;
    const float m  = fmaxf(a1, a2);
    const float nc = m + __log2f(exp2f(a1 - m) + exp2f(a2 - m));
    return ((t >= 0) && (t <= tl)) ? nc : cur;
}

// One block per batch element, 16 waves. __launch_bounds__(1024,4): 4 waves/EU is this
// block's own floor, so declare it -> VGPR budget 128/thread (R7 bug: compiler capped at 32,
// demoting all software pipelines).
__global__ __launch_bounds__(1024, 4) void k_fused(const float* __restrict__ trans,
                                                   const float* __restrict__ pred,
                                                   const int* __restrict__ labels,
                                                   const int* __restrict__ act_lens,
                                                   const int* __restrict__ label_lens,
                                                   float* __restrict__ ws,
                                                   float* __restrict__ out) {
    const int b   = blockIdx.x;
    const int tid = threadIdx.x;
    const int wid = tid >> 6;      // 0..15
    const int l   = tid & 63;

    __shared__ uint   Pds[192 * 64];                 // 48 KB diag lattice (row r=d-1)
    __shared__ __align__(16) half_t EPH_L[U1 * EPS]; // 66 KB exp(pred) f16, padded stride
    __shared__ __align__(16) half_t TL[T * 64];      // 16 KB trans[t][labels[u]]
    __shared__ float  af[T], C0[T], MT[T], T0[T];
    __shared__ float  MP[U1], P0[U1], PL[U1];

    half_t* ethb = (half_t*)ws + (size_t)b * T * V;  // this b's exp(trans) f16 rows (global)

    const int ul = label_lens[b];          // in [32,64]
    const int tl = act_lens[b] - 1;        // >= 63
    const int mylbl = labels[b * U + l];   // lane == u

    // ---- phase 1: row max + exp (f16) + gathers; 2-row software pipeline ----
    {
        const int NR = T + U1;             // 193 rows
        int r = wid;
        const float* src = (r < T) ? trans + ((size_t)b * T + r) * V
                                   : pred + ((size_t)b * U1 + (r - T)) * V;
        float4 a = ((const float4*)src)[l];
        float4 c = ((const float4*)src)[l + 64];
        while (true) {
            const int rn = r + NW;
            const float* src2 = src;
            float4 a2, c2;
            if (rn < NR) {                 // issue next row's loads before this row's math
                src2 = (rn < T) ? trans + ((size_t)b * T + rn) * V
                                : pred + ((size_t)b * U1 + (rn - T)) * V;
                a2 = ((const float4*)src2)[l];
                c2 = ((const float4*)src2)[l + 64];
            }

            float m = fmaxf(fmaxf(fmaxf(a.x, a.y), fmaxf(a.z, a.w)),
                            fmaxf(fmaxf(c.x, c.y), fmaxf(c.z, c.w)));
            #pragma unroll
            for (int off = 32; off >= 1; off >>= 1) m = fmaxf(m, __shfl_xor(m, off));

            v4h h0 = { (half_t)__expf(a.x - m), (half_t)__expf(a.y - m),
                       (half_t)__expf(a.z - m), (half_t)__expf(a.w - m) };
            v4h h1 = { (half_t)__expf(c.x - m), (half_t)__expf(c.y - m),
                       (half_t)__expf(c.z - m), (half_t)__expf(c.w - m) };
            if (r < T) {
                half_t* dst = ethb + (size_t)r * V;         // global (phase-2 A side)
                ((v4h*)dst)[l] = h0; ((v4h*)dst)[l + 64] = h1;
                TL[r * 64 + l] = (half_t)src[mylbl];
                if (l == 0) { MT[r] = m; T0[r] = a.x; }
            } else {
                const int u = r - T;
                half_t* dst = EPH_L + u * EPS;              // LDS (phase-2 B side)
                *(v4h*)(dst + 4 * l)       = h0;
                *(v4h*)(dst + 256 + 4 * l) = h1;
                if (l == u && l < U) PL[l] = src[mylbl];    // lane u owns its label
                if (l == 0) { MP[u] = m; P0[u] = a.x; }
            }

            if (rn >= NR) break;
            r = rn; src = src2; a = a2; c = c2;
        }
    }
    __threadfence_block();
    __syncthreads();

    // ---- phase 2: MFMA joint GEMM; A pipelined from global (L2-hot), B from LDS ----
    {
        const int n = l & 15, q = l >> 4;
        for (int task = wid; task < 40; task += NW) {
            const int t0 = (task / 5) * 16, u0 = (task % 5) * 16;
            const v8h* Ag = (const v8h*)(ethb + (size_t)(t0 + n) * V);
            const int uc = (u0 + n <= 64) ? (u0 + n) : 64;
            const half_t* Bl = EPH_L + uc * EPS;

            v4f acc = {0.f, 0.f, 0.f, 0.f};
            v8h Aa[4], An[4];                       // constant-indexed after unroll
            #pragma unroll
            for (int j = 0; j < 4; ++j) Aa[j] = Ag[j * 4 + q];
            #pragma unroll
            for (int g = 0; g < 4; ++g) {
                if (g < 3) {
                    #pragma unroll
                    for (int j = 0; j < 4; ++j) An[j] = Ag[((g + 1) * 4 + j) * 4 + q];
                }
                #pragma unroll
                for (int j = 0; j < 4; ++j) {
                    const int s = g * 4 + j;
                    const v8h Bf = *(const v8h*)(Bl + s * 32 + q * 8);  // ds_read_b128
                    acc = __builtin_amdgcn_mfma_f32_16x16x32_f16(Aa[j], Bf, acc, 0, 0, 0);
                }
                if (g < 3) {
                    #pragma unroll
                    for (int j = 0; j < 4; ++j) Aa[j] = An[j];
                }
            }

            const int u = u0 + n;                  // C/D: col=lane&15 -> u, row=q*4+i -> t
            if (u > 64) continue;
            const float mp_u = MP[u], pr0 = P0[u];
            const bool has_lab = (u < 64);
            const float prl = has_lab ? PL[u] : 0.f;
            #pragma unroll
            for (int i = 0; i < 4; ++i) {
                const int t = t0 + q * 4 + i;
                const float lse2 = (MT[t] + mp_u) * L2E + __log2f(acc[i]);
                const float bl2 = (T0[t] + pr0) * L2E - lse2;     // blank~[t][u]
                const int row = t + u;                            // = d-1
                if (u >= 1) ((half_t*)&Pds[row * 64 + (u - 1)])[0] = (half_t)bl2;
                else        C0[t] = bl2;
                if (has_lab) {
                    const float lb2 = (u >= ul) ? NEG2
                                     : ((float)TL[t * 64 + u] + prl) * L2E - lse2;  // lab~[t][u]
                    ((half_t*)&Pds[row * 64 + u])[1] = (half_t)lb2;
                }
            }
        }
    }
    __syncthreads();

    // ---- phase 3: anti-diagonal DP, wave 0 only ----
    if (wid != 0) return;

    float x0 = C0[l], x1 = C0[64 + l];     // alpha0 column: prefix scan of C0
    #pragma unroll
    for (int off = 1; off < 64; off <<= 1) { float y = __shfl_up(x0, off); if (l >= off) x0 += y; }
    #pragma unroll
    for (int off = 1; off < 64; off <<= 1) { float y = __shfl_up(x1, off); if (l >= off) x1 += y; }
    const float tot = __shfl(x0, 63);
    if (l == 0) af[0] = 0.0f;
    af[l + 1] = x0;                        // t = 1..64
    if (l < 63) af[65 + l] = tot + x1;     // t = 65..127

    const int dmax = tl + ul;              // <= 191
    const int steps = (dmax + 3) >> 2;     // overshoot steps are no-ops (t>tl guard)

    uint  w0 = Pds[0 * 64 + l], w1 = Pds[1 * 64 + l], w2 = Pds[2 * 64 + l], w3 = Pds[3 * 64 + l];
    float a0 = af[0], a1 = af[1], a2 = af[2], a3 = af[3];

    float cur = 0.0f;                      // lane l owns u = l+1; at step d, t = d-l-1
    int d = 1;
    for (int s = 0; s < steps; ++s) {
        cur = dp_step(cur, w0, a0, d, l, tl);
        w0 = Pds[min(d + 3, 191) * 64 + l]; a0 = af[min(d + 3, T - 1)]; ++d;
        cur = dp_step(cur, w1, a1, d, l, tl);
        w1 = Pds[min(d + 3, 191) * 64 + l]; a1 = af[min(d + 3, T - 1)]; ++d;
        cur = dp_step(cur, w2, a2, d, l, tl);
        w2 = Pds[min(d + 3, 191) * 64 + l]; a2 = af[min(d + 3, T - 1)]; ++d;
        cur = dp_step(cur, w3, a3, d, l, tl);
        w3 = Pds[min(d + 3, 191) * 64 + l]; a3 = af[min(d + 3, T - 1)]; ++d;
    }

    if (l == ul - 1) {                     // cur == alpha~[tl][ul]
        union { uint u; half_t h[2]; } cv; cv.u = Pds[dmax * 64 + (ul - 1)]; // d = dmax+1
        atomicAdd(out, -((cur + (float)cv.h[0]) * LN2));
    }
}

extern "C" void kernel_launch(void* const* d_in, const int* in_sizes, int n_in,
                              void* d_out, int out_size, void* d_ws, size_t ws_size,
                              hipStream_t stream) {
    const float* trans      = (const float*)d_in[0];
    const float* pred       = (const float*)d_in[1];
    const int*   labels     = (const int*)d_in[2];
    const int*   act_lens   = (const int*)d_in[3];
    const int*   label_lens = (const int*)d_in[4];
    float* ws  = (float*)d_ws;
    float* out = (float*)d_out;

    hipMemsetAsync(out, 0, sizeof(float), stream);   // graph-capturable memset node
    k_fused<<<B, 1024, 0, stream>>>(trans, pred, labels, act_lens, label_lens, ws, out);
}

// Round 9
// 98.391 us; speedup vs baseline: 1.2872x; 1.1180x over previous
//
#include <hip/hip_runtime.h>

// log2-domain "log 0": exp2(-30000) == 0, exactly representable in half, never NaN.
#define NEG2 (-30000.0f)
#define L2E  1.4426950408889634f
#define LN2  0.6931471805599453f

constexpr int B = 8, T = 128, U = 64, U1 = 65, V = 512;
constexpr int PDROWS = 200;
constexpr int PDW = PDROWS * 64;       // half2-words per b

// ws layout (float units): C0 column then diag lattice
constexpr int C0_F = 0;                // blank~[t][0] col (log2): B*T f32
constexpr int PD_F = C0_F + B * T;     // diag half2 lattice: B*PDW words
// Pd word (d,l): x = blank~[d-l-2][l+1], y = lab~[d-l-1][l]  (log2 domain)

typedef _Float16 half_t;
typedef _Float16 v8h __attribute__((ext_vector_type(8)));
typedef float    v4f __attribute__((ext_vector_type(4)));

__device__ __forceinline__ float wave_shr1(float x) {  // lane i <- lane i-1 (lane0 keeps own)
    int v = __float_as_int(x);
    int r = __builtin_amdgcn_update_dpp(v, v, 0x138, 0xF, 0xF, false); // wave_shr:1
    return __int_as_float(r);
}

__device__ __forceinline__ float dp_step(float cur, uint w, float a00, int d, int l, int tl) {
    const int t = d - l - 1;
    union { uint u; half_t h[2]; } cv; cv.u = w;
    const float bn = (float)cv.h[0];       // blank~[t-1][u]
    const float lb = (float)cv.h[1];       // lab~[t][u-1]
    const float sh = wave_shr1(cur);
    const float lv = (l == 0) ? a00 : sh;  // alpha[t][u-1]
    const float a2 = lv + lb;
    const float a1 = (t >= 1) ? cur + bn : NEG2;
    const float m  = fmaxf(a1, a2);
    const float nc = m + __log2f(exp2f(a1 - m) + exp2f(a2 - m));
    return ((t >= 0) && (t <= tl)) ? nc : cur;
}

// ---------------- k_joint: fused exp + MFMA GEMM + epilogue, full-machine parallel ----
// 80 blocks x 4 waves = 320 waves = 8 b x 40 tiles. Each wave: one 16x16 (t,u) tile,
// f32 rows loaded directly (L2-hot), row-max + exp in registers, 16 MFMAs, diag epilogue.
__global__ __launch_bounds__(256, 1) void k_joint(const float* __restrict__ trans,
                                                  const float* __restrict__ pred,
                                                  const int* __restrict__ labels,
                                                  const int* __restrict__ label_lens,
                                                  float* __restrict__ ws,
                                                  float* __restrict__ out) {
    if (blockIdx.x == 0 && threadIdx.x == 0) out[0] = 0.0f;  // consumed only by k_dp (next dispatch)

    const int wid = threadIdx.x >> 6, l = threadIdx.x & 63;
    const int n = l & 15, q = l >> 4;
    const int b    = blockIdx.x / 10;
    const int task = (blockIdx.x % 10) * 4 + wid;            // 0..39
    const int t0 = (task / 5) * 16, u0 = (task % 5) * 16;

    __shared__ float SMT[4][16], ST0[4][16], SMP[4][16], SP0[4][16], SPL[4][16];

    const float*  Arow = trans + ((size_t)b * T + t0 + n) * V;
    const int     ur   = (u0 + n <= 64) ? (u0 + n) : 64;
    const float*  Brow = pred + ((size_t)b * U1 + ur) * V;
    const float4* A4 = (const float4*)Arow;
    const float4* B4 = (const float4*)Brow;

    // ---- pass 1: full-row maxes; lane covers chunk [q*128, q*128+128) of its 2 rows ----
    float mA = -1e30f, mB = -1e30f, a0x = 0.f, b0x = 0.f;
    #pragma unroll 16
    for (int i = 0; i < 32; ++i) {
        const float4 va = A4[q * 32 + i];
        const float4 vb = B4[q * 32 + i];
        if (i == 0 && q == 0) { a0x = va.x; b0x = vb.x; }
        mA = fmaxf(mA, fmaxf(fmaxf(va.x, va.y), fmaxf(va.z, va.w)));
        mB = fmaxf(mB, fmaxf(fmaxf(vb.x, vb.y), fmaxf(vb.z, vb.w)));
    }
    mA = fmaxf(mA, __shfl_xor(mA, 16)); mA = fmaxf(mA, __shfl_xor(mA, 32));
    mB = fmaxf(mB, __shfl_xor(mB, 16)); mB = fmaxf(mB, __shfl_xor(mB, 32));

    if (q == 0) {                      // lane owns row t0+n (A) and row ur (B)
        SMT[wid][n] = mA; ST0[wid][n] = a0x;
        SMP[wid][n] = mB; SP0[wid][n] = b0x;
        SPL[wid][n] = (u0 + n < U) ? Brow[labels[b * U + u0 + n]] : 0.f;
    }

    // ---- pass 2: exp to f16 frags (L1/L2-hot reload) + MFMA; step s covers k=s*32+q*8..+7 ----
    v4f acc = {0.f, 0.f, 0.f, 0.f};
    #pragma unroll 4
    for (int s = 0; s < 16; ++s) {
        const float4 fa0 = A4[s * 8 + q * 2], fa1 = A4[s * 8 + q * 2 + 1];
        const float4 fb0 = B4[s * 8 + q * 2], fb1 = B4[s * 8 + q * 2 + 1];
        const v8h Af = { (half_t)__expf(fa0.x - mA), (half_t)__expf(fa0.y - mA),
                         (half_t)__expf(fa0.z - mA), (half_t)__expf(fa0.w - mA),
                         (half_t)__expf(fa1.x - mA), (half_t)__expf(fa1.y - mA),
                         (half_t)__expf(fa1.z - mA), (half_t)__expf(fa1.w - mA) };
        const v8h Bf = { (half_t)__expf(fb0.x - mB), (half_t)__expf(fb0.y - mB),
                         (half_t)__expf(fb0.z - mB), (half_t)__expf(fb0.w - mB),
                         (half_t)__expf(fb1.x - mB), (half_t)__expf(fb1.y - mB),
                         (half_t)__expf(fb1.z - mB), (half_t)__expf(fb1.w - mB) };
        acc = __builtin_amdgcn_mfma_f32_16x16x32_f16(Af, Bf, acc, 0, 0, 0);
    }

    // ---- epilogue: C/D col=lane&15 -> u, row=q*4+i -> t; write diag lattice ----
    const int u = u0 + n;
    if (u > 64) return;
    const int ul = label_lens[b];
    const float mp_u = SMP[wid][n], pr0 = SP0[wid][n];
    const bool has_lab = (u < U);
    const float prl = has_lab ? SPL[wid][n] : 0.f;
    const int lblu = has_lab ? labels[b * U + u] : 0;
    half_t* PdH = (half_t*)((uint*)(ws + PD_F) + (size_t)b * PDW);

    #pragma unroll
    for (int i = 0; i < 4; ++i) {
        const int t = t0 + q * 4 + i;
        const float mt = SMT[wid][q * 4 + i];
        const float lse2 = (mt + mp_u) * L2E + __log2f(acc[i]);
        const float bl2 = (ST0[wid][q * 4 + i] + pr0) * L2E - lse2;   // blank~[t][u]
        const int d = t + u + 1;
        if (u >= 1) PdH[(d * 64 + (u - 1)) * 2] = (half_t)bl2;
        else        ws[C0_F + b * T + t] = bl2;
        if (has_lab) {
            const float lb2 = (u >= ul) ? NEG2
                             : (trans[((size_t)b * T + t) * V + lblu] + prl) * L2E - lse2;
            PdH[(d * 64 + u) * 2 + 1] = (half_t)lb2;                  // lab~[t][u]
        }
    }
}

// ---------------- k_dp: anti-diagonal DP, one wave per b (R5-proven rotation) ----------------
__global__ __launch_bounds__(64) void k_dp(const float* __restrict__ ws,
                                           const int* __restrict__ act_lens,
                                           const int* __restrict__ label_lens,
                                           float* __restrict__ out) {
    const int b = blockIdx.x, l = threadIdx.x;

    constexpr int DROWS = 192;                 // diag rows 1..192 staged at idx d-1
    __shared__ uint Pds[DROWS * 64];           // 48 KB
    __shared__ float af[T];                    // alpha~[t][0] column

    const uint4* src4 = (const uint4*)((const uint*)(ws + PD_F) + (size_t)b * PDW + 64);
    uint4* dst4 = (uint4*)Pds;
    #pragma unroll
    for (int i = 0; i < DROWS / 4; ++i)
        dst4[i * 64 + l] = src4[i * 64 + l];

    const float* c0 = ws + C0_F + b * T;
    float x0 = c0[l], x1 = c0[64 + l];
    #pragma unroll
    for (int off = 1; off < 64; off <<= 1) { float y = __shfl_up(x0, off); if (l >= off) x0 += y; }
    #pragma unroll
    for (int off = 1; off < 64; off <<= 1) { float y = __shfl_up(x1, off); if (l >= off) x1 += y; }
    const float tot = __shfl(x0, 63);
    if (l == 0) af[0] = 0.0f;
    af[l + 1] = x0;                            // t = 1..64
    if (l < 63) af[65 + l] = tot + x1;         // t = 65..127
    __syncthreads();

    const int tl = act_lens[b] - 1;            // >= 63
    const int ul = label_lens[b];              // in [32,64]
    const int dmax = tl + ul;                  // <= 191
    const int steps = (dmax + 3) >> 2;         // overshoot steps are no-ops (t>tl guard)

    uint  w0 = Pds[0 * 64 + l], w1 = Pds[1 * 64 + l], w2 = Pds[2 * 64 + l], w3 = Pds[3 * 64 + l];
    float a0 = af[0], a1 = af[1], a2 = af[2], a3 = af[3];

    float cur = 0.0f;                          // lane l owns u = l+1; at step d, t = d-l-1
    int d = 1;
    for (int s = 0; s < steps; ++s) {
        cur = dp_step(cur, w0, a0, d, l, tl);
        w0 = Pds[min(d + 3, DROWS - 1) * 64 + l]; a0 = af[min(d + 3, T - 1)]; ++d;
        cur = dp_step(cur, w1, a1, d, l, tl);
        w1 = Pds[min(d + 3, DROWS - 1) * 64 + l]; a1 = af[min(d + 3, T - 1)]; ++d;
        cur = dp_step(cur, w2, a2, d, l, tl);
        w2 = Pds[min(d + 3, DROWS - 1) * 64 + l]; a2 = af[min(d + 3, T - 1)]; ++d;
        cur = dp_step(cur, w3, a3, d, l, tl);
        w3 = Pds[min(d + 3, DROWS - 1) * 64 + l]; a3 = af[min(d + 3, T - 1)]; ++d;
    }

    if (l == ul - 1) {                         // cur == alpha~[tl][ul]
        union { uint u; half_t h[2]; } cv; cv.u = Pds[dmax * 64 + (ul - 1)]; // row dmax+1
        atomicAdd(out, -((cur + (float)cv.h[0]) * LN2));
    }
}

extern "C" void kernel_launch(void* const* d_in, const int* in_sizes, int n_in,
                              void* d_out, int out_size, void* d_ws, size_t ws_size,
                              hipStream_t stream) {
    const float* trans      = (const float*)d_in[0];
    const float* pred       = (const float*)d_in[1];
    const int*   labels     = (const int*)d_in[2];
    const int*   act_lens   = (const int*)d_in[3];
    const int*   label_lens = (const int*)d_in[4];
    float* ws  = (float*)d_ws;
    float* out = (float*)d_out;

    k_joint<<<80, 256, 0, stream>>>(trans, pred, labels, label_lens, ws, out);
    k_dp<<<8, 64, 0, stream>>>(ws, act_lens, label_lens, out);
}